// Round 2
// baseline (534.407 us; speedup 1.0000x reference)
//
#include <hip/hip_runtime.h>
#include <hip/hip_bf16.h>

typedef short bf16x8 __attribute__((ext_vector_type(8)));
typedef float f32x4  __attribute__((ext_vector_type(4)));

#define SEQ  2048
#define HD   64
#define LDT  72      // staged-tile row stride (bf16): 144B rows, 16B-aligned for ds_*_b128
#define TSTR 80      // T/P scratch stride (bf16): 160B rows, 16B-aligned, >= 79 diagonals
#define NT   528     // causal 64x64 tiles per (b,h)
#define OUT0 (16 * SEQ * HD)   // weights offset in d_out (output tensor comes first)

__device__ __forceinline__ short f2bf(float x) {
    unsigned u = __float_as_uint(x);
    unsigned r = u + 0x7fffu + ((u >> 16) & 1u);   // RNE
    return (short)(r >> 16);
}
__device__ __forceinline__ float bf2f(short s) {
    return __uint_as_float(((unsigned)(unsigned short)s) << 16);
}

// stage a 64x64 f32 tile (row-major, row stride HD) -> bf16 LDS [64][LDT]
__device__ __forceinline__ void stage64(const float* __restrict__ src_base,
                                        short* __restrict__ dst, int tid) {
    const int r = tid >> 2, cg = tid & 3;
    const float4* src = (const float4*)(src_base + (size_t)r * HD + cg * 16);
    float f[16];
#pragma unroll
    for (int t = 0; t < 4; ++t) {
        float4 v4 = src[t];
        f[4*t] = v4.x; f[4*t+1] = v4.y; f[4*t+2] = v4.z; f[4*t+3] = v4.w;
    }
    bf16x8 p0, p1;
#pragma unroll
    for (int t = 0; t < 8; ++t) { p0[t] = f2bf(f[t]); p1[t] = f2bf(f[t+8]); }
    *(bf16x8*)&dst[r * LDT + cg * 16]     = p0;
    *(bf16x8*)&dst[r * LDT + cg * 16 + 8] = p1;
}

// stage G[dd][k] = E[1086 - i0 + j0 - dd][k] (or 0) for dd in [0,128)
__device__ __forceinline__ void stageG(const float* __restrict__ eg,
                                       short* __restrict__ Gs, int tid, int i0, int j0) {
    const int dd = tid >> 1, hf = tid & 1;
    const int e = 1086 - i0 + j0 - dd;
    short* dst = &Gs[dd * LDT + hf * 32];
    if (e >= 0 && e < 1024) {
        const float4* src = (const float4*)(eg + (size_t)e * HD + hf * 32);
#pragma unroll
        for (int u = 0; u < 4; ++u) {
            float4 a = src[2*u], b = src[2*u + 1];
            bf16x8 p;
            p[0] = f2bf(a.x); p[1] = f2bf(a.y); p[2] = f2bf(a.z); p[3] = f2bf(a.w);
            p[4] = f2bf(b.x); p[5] = f2bf(b.y); p[6] = f2bf(b.z); p[7] = f2bf(b.w);
            *(bf16x8*)&dst[u * 8] = p;
        }
    } else {
        bf16x8 z = {0,0,0,0,0,0,0,0};
#pragma unroll
        for (int u = 0; u < 4; ++u) *(bf16x8*)&dst[u * 8] = z;
    }
}

// stage V transposed into Vt[dim][key]
__device__ __forceinline__ void stageV(const float* __restrict__ src_base,
                                       short* __restrict__ Vt, int tid) {
    const int r = tid >> 2, cg = tid & 3;
    const float4* src = (const float4*)(src_base + (size_t)r * HD + cg * 16);
    float f[16];
#pragma unroll
    for (int t = 0; t < 4; ++t) {
        float4 v4 = src[t];
        f[4*t] = v4.x; f[4*t+1] = v4.y; f[4*t+2] = v4.z; f[4*t+3] = v4.w;
    }
#pragma unroll
    for (int t = 0; t < 16; ++t) Vt[(cg * 16 + t) * LDT + r] = f2bf(f[t]);
}

// S = Q@K^T + skewed rel (via T = Q@G^T round-tripped through wave-local LDS), masked
__device__ __forceinline__ void compute_sc(const bf16x8* aq, const short* __restrict__ Ks,
                                           const short* __restrict__ Gs, short* __restrict__ Tw,
                                           int wv, int qd, int c, int i0, int j0, f32x4* sc) {
    f32x4 tc[5];
    const f32x4 zz = {0.f, 0.f, 0.f, 0.f};
#pragma unroll
    for (int ct = 0; ct < 4; ++ct) sc[ct] = zz;
#pragma unroll
    for (int dt = 0; dt < 5; ++dt) tc[dt] = zz;
#pragma unroll
    for (int s = 0; s < 2; ++s) {
        bf16x8 a = aq[s];
#pragma unroll
        for (int ct = 0; ct < 4; ++ct) {
            bf16x8 b = *(const bf16x8*)&Ks[(ct * 16 + c) * LDT + s * 32 + qd * 8];
            sc[ct] = __builtin_amdgcn_mfma_f32_16x16x32_bf16(a, b, sc[ct], 0, 0, 0);
        }
#pragma unroll
        for (int dt = 0; dt < 5; ++dt) {
            bf16x8 g = *(const bf16x8*)&Gs[((wv + dt) * 16 + c) * LDT + s * 32 + qd * 8];
            tc[dt] = __builtin_amdgcn_mfma_f32_16x16x32_bf16(a, g, tc[dt], 0, 0, 0);
        }
    }
#pragma unroll
    for (int dt = 0; dt < 5; ++dt)
#pragma unroll
        for (int rg = 0; rg < 4; ++rg)
            Tw[(qd * 4 + rg) * TSTR + dt * 16 + c] = f2bf(tc[dt][rg]);
#pragma unroll
    for (int ct = 0; ct < 4; ++ct)
#pragma unroll
        for (int rg = 0; rg < 4; ++rg) {
            const int rl  = qd * 4 + rg;
            const int ddl = rl + 63 - ct * 16 - c;          // in [0,78]
            float sval = sc[ct][rg] + bf2f(Tw[rl * TSTR + ddl]);
            const int ig = i0 + wv * 16 + rl;
            const int jg = j0 + ct * 16 + c;
            sc[ct][rg] = (jg <= ig) ? sval : -3.0e38f;
        }
}

// ============ single-pass kernel: p = exp(S) staged to ws, normalize after ============
__global__ __launch_bounds__(256, 3)
void relattn_1p(const float* __restrict__ qg, const float* __restrict__ kg,
                const float* __restrict__ vg, const float* __restrict__ eg,
                float* __restrict__ outp, short* __restrict__ wsp)
{
    __shared__ short QT[4 * 16 * TSTR];  // Q staging (stride LDT), then per-wave T/P scratch
    __shared__ short Ks[64 * LDT];
    __shared__ short Vt[64 * LDT];
    __shared__ short Gs[128 * LDT];

    const int tid  = threadIdx.x;
    const int wv   = tid >> 6;
    const int lane = tid & 63;
    const int qd   = lane >> 4;
    const int c    = lane & 15;

    const int bh = blockIdx.x & 15;
    const int qt = 31 - (blockIdx.x >> 4);
    const int i0 = qt * 64;

    float* Wg = outp + OUT0;

    // zero-fill fully-masked column region of weights
    {
        const int z0v = (qt + 1) * 16;
        for (int r = 0; r < 64; ++r) {
            float4* dst = (float4*)(Wg + ((size_t)(bh * SEQ + i0 + r)) * SEQ);
            for (int jv = z0v + tid; jv < SEQ / 4; jv += 256)
                dst[jv] = make_float4(0.f, 0.f, 0.f, 0.f);
        }
    }

    stage64(qg + ((size_t)(bh * SEQ + i0)) * HD, QT, tid);
    __syncthreads();
    bf16x8 aq[2];
#pragma unroll
    for (int s = 0; s < 2; ++s)
        aq[s] = *(const bf16x8*)&QT[(wv * 16 + c) * LDT + s * 32 + qd * 8];
    short* Tw = &QT[wv * 16 * TSTR];   // aliases Qs — safe: aq consumed before next barrier

    float lrun[4] = {0.f, 0.f, 0.f, 0.f};
    f32x4 ob[4];
    {
        const f32x4 zz = {0.f, 0.f, 0.f, 0.f};
#pragma unroll
        for (int dt = 0; dt < 4; ++dt) ob[dt] = zz;
    }

    const int tri = qt * (qt + 1) / 2;
    const size_t wsbase = (((size_t)bh * NT + tri) << 12) + (size_t)(wv * 1024 + lane * 16);

    for (int kt = 0; kt <= qt; ++kt) {
        const int j0 = kt * 64;
        __syncthreads();
        stage64(kg + ((size_t)(bh * SEQ + j0)) * HD, Ks, tid);
        stageG(eg, Gs, tid, i0, j0);
        stageV(vg + ((size_t)(bh * SEQ + j0)) * HD, Vt, tid);
        __syncthreads();

        f32x4 sc[4];
        compute_sc(aq, Ks, Gs, Tw, wv, qd, c, i0, j0, sc);

        float p[4][4];
#pragma unroll
        for (int ct = 0; ct < 4; ++ct)
#pragma unroll
            for (int rg = 0; rg < 4; ++rg)
                p[ct][rg] = __expf(sc[ct][rg]);   // masked -> exp(-huge) = 0

        // row sums (reduce over the 16 c-lanes)
#pragma unroll
        for (int rg = 0; rg < 4; ++rg) {
            float ss = p[0][rg] + p[1][rg] + p[2][rg] + p[3][rg];
            ss += __shfl_xor(ss, 1);
            ss += __shfl_xor(ss, 2);
            ss += __shfl_xor(ss, 4);
            ss += __shfl_xor(ss, 8);
            lrun[rg] += ss;
        }

        // pack p -> bf16, stream to ws (coalesced 32B/lane), also to LDS for PV A-frags
        __align__(16) short pk[16];
#pragma unroll
        for (int ct = 0; ct < 4; ++ct)
#pragma unroll
            for (int rg = 0; rg < 4; ++rg)
                pk[ct * 4 + rg] = f2bf(p[ct][rg]);
        short* wst = wsp + (wsbase + ((size_t)kt << 12));
        *(bf16x8*)wst       = *(bf16x8*)&pk[0];
        *(bf16x8*)(wst + 8) = *(bf16x8*)&pk[8];
#pragma unroll
        for (int ct = 0; ct < 4; ++ct)
#pragma unroll
            for (int rg = 0; rg < 4; ++rg)
                Tw[(qd * 4 + rg) * TSTR + ct * 16 + c] = pk[ct * 4 + rg];

        // O += P_unnorm @ V
#pragma unroll
        for (int s = 0; s < 2; ++s) {
            bf16x8 ap = *(const bf16x8*)&Tw[c * TSTR + s * 32 + qd * 8];
#pragma unroll
            for (int dt = 0; dt < 4; ++dt) {
                bf16x8 bv = *(const bf16x8*)&Vt[(dt * 16 + c) * LDT + s * 32 + qd * 8];
                ob[dt] = __builtin_amdgcn_mfma_f32_16x16x32_bf16(ap, bv, ob[dt], 0, 0, 0);
            }
        }
    }

    __syncthreads();     // drains vmcnt(0): all ws stores complete
    __threadfence();     // device fence: no stale L1 on read-back

    float linv[4];
#pragma unroll
    for (int rg = 0; rg < 4; ++rg) linv[rg] = 1.0f / lrun[rg];

    // O = ob / l
#pragma unroll
    for (int dt = 0; dt < 4; ++dt)
#pragma unroll
        for (int rg = 0; rg < 4; ++rg) {
            const int ig = i0 + wv * 16 + qd * 4 + rg;
            outp[((size_t)(bh * SEQ + ig)) * HD + dt * 16 + c] = ob[dt][rg] * linv[rg];
        }

    // W = p / l : re-read own p tiles from ws, scale, store
    float* rowp[4];
#pragma unroll
    for (int rg = 0; rg < 4; ++rg)
        rowp[rg] = Wg + ((size_t)(bh * SEQ + i0 + wv * 16 + qd * 4 + rg)) * SEQ + c;

    for (int kt = 0; kt <= qt; ++kt) {
        const short* wst = wsp + (wsbase + ((size_t)kt << 12));
        bf16x8 a0 = *(const bf16x8*)wst;
        bf16x8 a1 = *(const bf16x8*)(wst + 8);
        const int j0 = kt * 64;
#pragma unroll
        for (int v = 0; v < 8; ++v) {
            const int ct = v >> 2, rg = v & 3;
            rowp[rg][j0 + ct * 16] = bf2f(a0[v]) * linv[rg];
        }
#pragma unroll
        for (int v = 0; v < 8; ++v) {
            const int u = v + 8, ct = u >> 2, rg = u & 3;
            rowp[rg][j0 + ct * 16] = bf2f(a1[v]) * linv[rg];
        }
    }
}

// ============ fallback (ws too small): two-pass, same LDS-sharing, m=0 ============
__global__ __launch_bounds__(256, 3)
void relattn_2p(const float* __restrict__ qg, const float* __restrict__ kg,
                const float* __restrict__ vg, const float* __restrict__ eg,
                float* __restrict__ outp)
{
    __shared__ short QT[4 * 16 * TSTR];
    __shared__ short Ks[64 * LDT];
    __shared__ short Vt[64 * LDT];
    __shared__ short Gs[128 * LDT];

    const int tid  = threadIdx.x;
    const int wv   = tid >> 6;
    const int lane = tid & 63;
    const int qd   = lane >> 4;
    const int c    = lane & 15;

    const int bh = blockIdx.x & 15;
    const int qt = 31 - (blockIdx.x >> 4);
    const int i0 = qt * 64;
    float* Wg = outp + OUT0;

    {
        const int z0v = (qt + 1) * 16;
        for (int r = 0; r < 64; ++r) {
            float4* dst = (float4*)(Wg + ((size_t)(bh * SEQ + i0 + r)) * SEQ);
            for (int jv = z0v + tid; jv < SEQ / 4; jv += 256)
                dst[jv] = make_float4(0.f, 0.f, 0.f, 0.f);
        }
    }

    stage64(qg + ((size_t)(bh * SEQ + i0)) * HD, QT, tid);
    __syncthreads();
    bf16x8 aq[2];
#pragma unroll
    for (int s = 0; s < 2; ++s)
        aq[s] = *(const bf16x8*)&QT[(wv * 16 + c) * LDT + s * 32 + qd * 8];
    short* Tw = &QT[wv * 16 * TSTR];

    float lrun[4] = {0.f, 0.f, 0.f, 0.f};

    for (int kt = 0; kt <= qt; ++kt) {
        const int j0 = kt * 64;
        __syncthreads();
        stage64(kg + ((size_t)(bh * SEQ + j0)) * HD, Ks, tid);
        stageG(eg, Gs, tid, i0, j0);
        __syncthreads();
        f32x4 sc[4];
        compute_sc(aq, Ks, Gs, Tw, wv, qd, c, i0, j0, sc);
#pragma unroll
        for (int rg = 0; rg < 4; ++rg) {
            float ss = __expf(sc[0][rg]) + __expf(sc[1][rg]) + __expf(sc[2][rg]) + __expf(sc[3][rg]);
            ss += __shfl_xor(ss, 1);
            ss += __shfl_xor(ss, 2);
            ss += __shfl_xor(ss, 4);
            ss += __shfl_xor(ss, 8);
            lrun[rg] += ss;
        }
    }

    float linv[4];
#pragma unroll
    for (int rg = 0; rg < 4; ++rg) linv[rg] = 1.0f / lrun[rg];

    f32x4 ob[4];
    {
        const f32x4 zz = {0.f, 0.f, 0.f, 0.f};
#pragma unroll
        for (int dt = 0; dt < 4; ++dt) ob[dt] = zz;
    }

    for (int kt = 0; kt <= qt; ++kt) {
        const int j0 = kt * 64;
        __syncthreads();
        stage64(kg + ((size_t)(bh * SEQ + j0)) * HD, Ks, tid);
        stageG(eg, Gs, tid, i0, j0);
        stageV(vg + ((size_t)(bh * SEQ + j0)) * HD, Vt, tid);
        __syncthreads();
        f32x4 sc[4];
        compute_sc(aq, Ks, Gs, Tw, wv, qd, c, i0, j0, sc);
#pragma unroll
        for (int rg = 0; rg < 4; ++rg) {
            const int rl = qd * 4 + rg;
            const int ig = i0 + wv * 16 + rl;
            float* wrow = Wg + ((size_t)(bh * SEQ + ig)) * SEQ + j0;
#pragma unroll
            for (int ct = 0; ct < 4; ++ct) {
                const float w = __expf(sc[ct][rg]) * linv[rg];
                wrow[ct * 16 + c] = w;
                Tw[rl * TSTR + ct * 16 + c] = f2bf(w);
            }
        }
#pragma unroll
        for (int s = 0; s < 2; ++s) {
            bf16x8 ap = *(const bf16x8*)&Tw[c * TSTR + s * 32 + qd * 8];
#pragma unroll
            for (int dt = 0; dt < 4; ++dt) {
                bf16x8 bv = *(const bf16x8*)&Vt[(dt * 16 + c) * LDT + s * 32 + qd * 8];
                ob[dt] = __builtin_amdgcn_mfma_f32_16x16x32_bf16(ap, bv, ob[dt], 0, 0, 0);
            }
        }
    }

#pragma unroll
    for (int dt = 0; dt < 4; ++dt)
#pragma unroll
        for (int rg = 0; rg < 4; ++rg) {
            const int ig = i0 + wv * 16 + qd * 4 + rg;
            outp[((size_t)(bh * SEQ + ig)) * HD + dt * 16 + c] = ob[dt][rg];
        }
}

extern "C" void kernel_launch(void* const* d_in, const int* in_sizes, int n_in,
                              void* d_out, int out_size, void* d_ws, size_t ws_size,
                              hipStream_t stream) {
    const float* q = (const float*)d_in[0];
    const float* k = (const float*)d_in[1];
    const float* v = (const float*)d_in[2];
    const float* e = (const float*)d_in[3];
    float* out = (float*)d_out;
    const size_t need = (size_t)16 * NT * 4096 * sizeof(short);   // 69.2 MB
    if (ws_size >= need)
        hipLaunchKernelGGL(relattn_1p, dim3(512), dim3(256), 0, stream, q, k, v, e, out, (short*)d_ws);
    else
        hipLaunchKernelGGL(relattn_2p, dim3(512), dim3(256), 0, stream, q, k, v, e, out);
}

// Round 3
// 466.664 us; speedup vs baseline: 1.1452x; 1.1452x over previous
//
#include <hip/hip_runtime.h>
#include <hip/hip_bf16.h>

typedef short bf16x8 __attribute__((ext_vector_type(8)));
typedef float f32x4  __attribute__((ext_vector_type(4)));

#define SEQ  2048
#define HD   64
#define NT   528     // causal 64x64 tiles per (b,h)
#define TSTR 80      // wave-private T/P scratch stride (bf16), >= 79 diagonals
#define LDT  72      // LDS stride for prep transpose
#define OUT0 (16 * SEQ * HD)

// ---- ws layout (shorts unless noted) ----
#define WS_P_SHORTS ((size_t)16 * NT * 4096)            // 34,603,008
#define WS_K_OFF    (WS_P_SHORTS)
#define WS_K_SHORTS ((size_t)16 * SEQ * HD)             // 2,097,152
#define WS_V_OFF    (WS_K_OFF + WS_K_SHORTS)
#define WS_V_SHORTS ((size_t)16 * SEQ * HD)
#define WS_E_OFF    (WS_V_OFF + WS_V_SHORTS)
#define WS_E_SHORTS ((size_t)2112 * 64)                 // 135,168
#define WS_L_OFF_B  ((WS_E_OFF + WS_E_SHORTS) * 2)     // byte offset of linv (f32)
#define WS_NEED     (WS_L_OFF_B + (size_t)16 * SEQ * 4) // 77,996,032 B

__device__ __forceinline__ short f2bf(float x) {
    unsigned u = __float_as_uint(x);
    unsigned r = u + 0x7fffu + ((u >> 16) & 1u);   // RNE
    return (short)(r >> 16);
}
__device__ __forceinline__ float bf2f(short s) {
    return __uint_as_float(((unsigned)(unsigned short)s) << 16);
}

// ================= prep: K->bf16, V->bf16 transposed, E->bf16 padded =================
__global__ __launch_bounds__(256)
void prep(const float* __restrict__ kg, const float* __restrict__ vg,
          const float* __restrict__ eg, short* __restrict__ wsp)
{
    const int b = blockIdx.x, tid = threadIdx.x;
    if (b < 512) {                       // V transpose: 16 bh x 32 key-tiles
        __shared__ short Vt[64 * LDT];
        const int bh = b & 15, j0 = (b >> 4) * 64;
        const int r = tid >> 2, cg = tid & 3;
        const float4* src = (const float4*)(vg + ((size_t)(bh * SEQ + j0 + r)) * HD + cg * 16);
        float f[16];
#pragma unroll
        for (int t = 0; t < 4; ++t) {
            float4 v4 = src[t];
            f[4*t] = v4.x; f[4*t+1] = v4.y; f[4*t+2] = v4.z; f[4*t+3] = v4.w;
        }
#pragma unroll
        for (int t = 0; t < 16; ++t) Vt[(cg * 16 + t) * LDT + r] = f2bf(f[t]);
        __syncthreads();
        const int dim = tid >> 2, pp = tid & 3;
        short* dst = wsp + WS_V_OFF + ((size_t)(bh * HD + dim)) * SEQ + j0 + pp * 16;
        *(bf16x8*)dst       = *(bf16x8*)&Vt[dim * LDT + pp * 16];
        *(bf16x8*)(dst + 8) = *(bf16x8*)&Vt[dim * LDT + pp * 16 + 8];
    } else if (b < 1024) {               // K convert (layout-preserving)
        const size_t el = ((size_t)(b - 512)) * 4096 + (size_t)tid * 16;
        const float4* src = (const float4*)(kg + el);
        short* dst = wsp + WS_K_OFF + el;
#pragma unroll
        for (int g = 0; g < 2; ++g) {
            float4 a = src[2*g], c = src[2*g + 1];
            bf16x8 p;
            p[0] = f2bf(a.x); p[1] = f2bf(a.y); p[2] = f2bf(a.z); p[3] = f2bf(a.w);
            p[4] = f2bf(c.x); p[5] = f2bf(c.y); p[6] = f2bf(c.z); p[7] = f2bf(c.w);
            *(bf16x8*)(dst + 8 * g) = p;
        }
    } else {                             // Epad: row idx = e + 1025, zeros outside [0,1024)
        const size_t gid = ((size_t)(b - 1024)) * 2048 + (size_t)tid * 8;
        const int row = (int)(gid >> 6), cc = (int)(gid & 63);
        const int e = row - 1025;
        bf16x8 p = {0,0,0,0,0,0,0,0};
        if (e >= 0 && e < 1024) {
            float4 a = *(const float4*)(eg + (size_t)e * HD + cc);
            float4 c = *(const float4*)(eg + (size_t)e * HD + cc + 4);
            p[0] = f2bf(a.x); p[1] = f2bf(a.y); p[2] = f2bf(a.z); p[3] = f2bf(a.w);
            p[4] = f2bf(c.x); p[5] = f2bf(c.y); p[6] = f2bf(c.z); p[7] = f2bf(c.w);
        }
        *(bf16x8*)(wsp + WS_E_OFF + gid) = p;
    }
}

// ================= attn: barrier-free k-loop, direct bf16 B-frag loads =================
__global__ __launch_bounds__(256, 3)
void attn(const float* __restrict__ qg, float* __restrict__ outp,
          short* __restrict__ wsp, float* __restrict__ lw)
{
    __shared__ short TP[4 * 16 * TSTR];   // wave-private scratch (no cross-wave use)

    const int tid  = threadIdx.x;
    const int wv   = tid >> 6;
    const int lane = tid & 63;
    const int qd   = lane >> 4;
    const int c    = lane & 15;

    const int bh = blockIdx.x & 15;
    const int qt = 31 - (blockIdx.x >> 4);   // heavy q-tiles first (LPT)
    const int i0 = qt * 64;

    const short* Kb = wsp + WS_K_OFF + (size_t)bh * SEQ * HD;
    const short* Vb = wsp + WS_V_OFF + (size_t)bh * HD * SEQ;
    const short* Eb = wsp + WS_E_OFF;
    short* Tw = &TP[wv * 16 * TSTR];

    // Q A-fragments: direct load + convert (row = i0 + wv*16 + c)
    const float* qrow = qg + ((size_t)(bh * SEQ + i0 + wv * 16 + c)) * HD;
    bf16x8 aq[2];
#pragma unroll
    for (int s = 0; s < 2; ++s) {
        float4 a = *(const float4*)(qrow + s * 32 + qd * 8);
        float4 b2 = *(const float4*)(qrow + s * 32 + qd * 8 + 4);
        bf16x8 p;
        p[0] = f2bf(a.x); p[1] = f2bf(a.y); p[2] = f2bf(a.z); p[3] = f2bf(a.w);
        p[4] = f2bf(b2.x); p[5] = f2bf(b2.y); p[6] = f2bf(b2.z); p[7] = f2bf(b2.w);
        aq[s] = p;
    }

    float lrun[4] = {0.f, 0.f, 0.f, 0.f};
    f32x4 ob[4];
    const f32x4 zz = {0.f, 0.f, 0.f, 0.f};
#pragma unroll
    for (int dt = 0; dt < 4; ++dt) ob[dt] = zz;

    const int tri = qt * (qt + 1) / 2;

    for (int kt = 0; kt <= qt; ++kt) {
        const int j0 = kt * 64;
        f32x4 sc[4], tc[5];
#pragma unroll
        for (int ct = 0; ct < 4; ++ct) sc[ct] = zz;
#pragma unroll
        for (int dt = 0; dt < 5; ++dt) tc[dt] = zz;

#pragma unroll
        for (int s = 0; s < 2; ++s) {
            const int off = s * 32 + qd * 8;
            bf16x8 a = aq[s];
#pragma unroll
            for (int ct = 0; ct < 4; ++ct) {
                bf16x8 bk = *(const bf16x8*)(Kb + (size_t)(j0 + ct * 16 + c) * HD + off);
                sc[ct] = __builtin_amdgcn_mfma_f32_16x16x32_bf16(a, bk, sc[ct], 0, 0, 0);
            }
#pragma unroll
            for (int dt = 0; dt < 5; ++dt) {
                const int idx = 2111 - i0 + j0 - ((wv + dt) * 16 + c);
                bf16x8 g = *(const bf16x8*)(Eb + (size_t)idx * 64 + off);
                tc[dt] = __builtin_amdgcn_mfma_f32_16x16x32_bf16(a, g, tc[dt], 0, 0, 0);
            }
        }

        // T C-frag -> wave-local LDS (row = qd*4+rg, col = dt*16+c)
#pragma unroll
        for (int dt = 0; dt < 5; ++dt)
#pragma unroll
            for (int rg = 0; rg < 4; ++rg)
                Tw[(qd * 4 + rg) * TSTR + dt * 16 + c] = f2bf(tc[dt][rg]);

        // S = QK + skew(T), mask, exp
        float p[4][4];
#pragma unroll
        for (int ct = 0; ct < 4; ++ct)
#pragma unroll
            for (int rg = 0; rg < 4; ++rg) {
                const int rl  = qd * 4 + rg;
                const int ddl = rl + 63 - ct * 16 - c;        // [0,78]
                const float sval = sc[ct][rg] + bf2f(Tw[rl * TSTR + ddl]);
                const int ig = i0 + wv * 16 + rl;
                const int jg = j0 + ct * 16 + c;
                p[ct][rg] = (jg <= ig) ? __expf(sval) : 0.0f;
            }

        // row sums over the 16 c-lanes
#pragma unroll
        for (int rg = 0; rg < 4; ++rg) {
            float ss = p[0][rg] + p[1][rg] + p[2][rg] + p[3][rg];
            ss += __shfl_xor(ss, 1);
            ss += __shfl_xor(ss, 2);
            ss += __shfl_xor(ss, 4);
            ss += __shfl_xor(ss, 8);
            lrun[rg] += ss;
        }

        // p -> Tw (row-major, overwrites T after all diagonal reads above)
#pragma unroll
        for (int ct = 0; ct < 4; ++ct)
#pragma unroll
            for (int rg = 0; rg < 4; ++rg)
                Tw[(qd * 4 + rg) * TSTR + ct * 16 + c] = f2bf(p[ct][rg]);

        // O += P @ V  (A-frag from Tw, B-frag direct from V^T bf16)
#pragma unroll
        for (int s = 0; s < 2; ++s) {
            bf16x8 ap = *(const bf16x8*)&Tw[c * TSTR + s * 32 + qd * 8];
#pragma unroll
            for (int dt = 0; dt < 4; ++dt) {
                bf16x8 bv = *(const bf16x8*)(Vb + (size_t)(dt * 16 + c) * SEQ + j0 + s * 32 + qd * 8);
                ob[dt] = __builtin_amdgcn_mfma_f32_16x16x32_bf16(ap, bv, ob[dt], 0, 0, 0);
            }
        }

        // p tile -> ws row-major (coalesced 32 B/lane)
        {
            const size_t tb = ((size_t)(bh * NT) + tri + kt) * 4096;
            const int rr = lane >> 2, c4 = (lane & 3) * 16;
            bf16x8 p0 = *(const bf16x8*)&Tw[rr * TSTR + c4];
            bf16x8 p1 = *(const bf16x8*)&Tw[rr * TSTR + c4 + 8];
            short* dst = wsp + tb + (size_t)(wv * 16 + rr) * 64 + c4;
            *(bf16x8*)dst       = p0;
            *(bf16x8*)(dst + 8) = p1;
        }
    }

    float linv[4];
#pragma unroll
    for (int rg = 0; rg < 4; ++rg) linv[rg] = 1.0f / lrun[rg];

#pragma unroll
    for (int dt = 0; dt < 4; ++dt)
#pragma unroll
        for (int rg = 0; rg < 4; ++rg) {
            const int ig = i0 + wv * 16 + qd * 4 + rg;
            outp[((size_t)(bh * SEQ + ig)) * HD + dt * 16 + c] = ob[dt][rg] * linv[rg];
        }

    if (c == 0) {
#pragma unroll
        for (int rg = 0; rg < 4; ++rg)
            lw[bh * SEQ + i0 + wv * 16 + qd * 4 + rg] = linv[rg];
    }
}

// ================= finw: stream W = p * linv (fully coalesced) =================
__global__ __launch_bounds__(256)
void finw(float* __restrict__ outp, const short* __restrict__ wsp,
          const float* __restrict__ lw)
{
    const int tid = threadIdx.x;
    const int wv = tid >> 6, lane = tid & 63;
    const int gr = blockIdx.x * 4 + wv;            // global row in [0, 32768)
    const int bh = gr >> 11, r = gr & 2047, qt = r >> 6;
    const float linv = lw[gr];
    const short* prow = wsp + ((size_t)(bh * NT) + (qt * (qt + 1)) / 2) * 4096
                        + (size_t)(r & 63) * 64;
    float* wrow = outp + OUT0 + (size_t)gr * SEQ;
    const int ncol = (qt + 1) * 64;

    for (int g = lane * 8; g < ncol; g += 512) {
        const int kt = g >> 6;
        bf16x8 a = *(const bf16x8*)(prow + (size_t)kt * 4096 + (g & 63));
        float4 o0, o1;
        o0.x = bf2f(a[0]) * linv; o0.y = bf2f(a[1]) * linv;
        o0.z = bf2f(a[2]) * linv; o0.w = bf2f(a[3]) * linv;
        o1.x = bf2f(a[4]) * linv; o1.y = bf2f(a[5]) * linv;
        o1.z = bf2f(a[6]) * linv; o1.w = bf2f(a[7]) * linv;
        *(float4*)(wrow + g)     = o0;
        *(float4*)(wrow + g + 4) = o1;
    }
    const float4 z = {0.f, 0.f, 0.f, 0.f};
    for (int g4 = ncol / 4 + lane; g4 < SEQ / 4; g4 += 64)
        ((float4*)wrow)[g4] = z;
}

// ================= fallback (ws too small): R1-style two-pass =================
__global__ __launch_bounds__(256, 3)
void relattn_2p(const float* __restrict__ qg, const float* __restrict__ kg,
                const float* __restrict__ vg, const float* __restrict__ eg,
                float* __restrict__ outp)
{
    __shared__ short QT[4 * 16 * TSTR];
    __shared__ short Ks[64 * LDT];
    __shared__ short Vt[64 * LDT];
    __shared__ short Gs[128 * LDT];

    const int tid  = threadIdx.x;
    const int wv   = tid >> 6;
    const int lane = tid & 63;
    const int qd   = lane >> 4;
    const int c    = lane & 15;

    const int bh = blockIdx.x & 15;
    const int qt = 31 - (blockIdx.x >> 4);
    const int i0 = qt * 64;
    float* Wg = outp + OUT0;

    {
        const int z0v = (qt + 1) * 16;
        for (int r = 0; r < 64; ++r) {
            float4* dst = (float4*)(Wg + ((size_t)(bh * SEQ + i0 + r)) * SEQ);
            for (int jv = z0v + tid; jv < SEQ / 4; jv += 256)
                dst[jv] = make_float4(0.f, 0.f, 0.f, 0.f);
        }
    }

    {   // stage Q
        const int r = tid >> 2, cg = tid & 3;
        const float4* src = (const float4*)(qg + ((size_t)(bh * SEQ + i0 + r)) * HD + cg * 16);
        float f[16];
#pragma unroll
        for (int t = 0; t < 4; ++t) {
            float4 v4 = src[t];
            f[4*t] = v4.x; f[4*t+1] = v4.y; f[4*t+2] = v4.z; f[4*t+3] = v4.w;
        }
        bf16x8 p0, p1;
#pragma unroll
        for (int t = 0; t < 8; ++t) { p0[t] = f2bf(f[t]); p1[t] = f2bf(f[t+8]); }
        *(bf16x8*)&QT[r * LDT + cg * 16]     = p0;
        *(bf16x8*)&QT[r * LDT + cg * 16 + 8] = p1;
    }
    __syncthreads();
    bf16x8 aq[2];
#pragma unroll
    for (int s = 0; s < 2; ++s)
        aq[s] = *(const bf16x8*)&QT[(wv * 16 + c) * LDT + s * 32 + qd * 8];
    short* Tw = &QT[wv * 16 * TSTR];

    float lrun[4] = {0.f, 0.f, 0.f, 0.f};
    f32x4 ob[4];
    const f32x4 zz = {0.f, 0.f, 0.f, 0.f};
#pragma unroll
    for (int dt = 0; dt < 4; ++dt) ob[dt] = zz;

    for (int pass = 0; pass < 2; ++pass) {
        float linv[4];
        if (pass == 1) {
#pragma unroll
            for (int rg = 0; rg < 4; ++rg) linv[rg] = 1.0f / lrun[rg];
        }
        for (int kt = 0; kt <= qt; ++kt) {
            const int j0 = kt * 64;
            __syncthreads();
            {   // stage K
                const int r = tid >> 2, cg = tid & 3;
                const float4* src = (const float4*)(kg + ((size_t)(bh * SEQ + j0 + r)) * HD + cg * 16);
                float f[16];
#pragma unroll
                for (int t = 0; t < 4; ++t) {
                    float4 v4 = src[t];
                    f[4*t] = v4.x; f[4*t+1] = v4.y; f[4*t+2] = v4.z; f[4*t+3] = v4.w;
                }
                bf16x8 p0, p1;
#pragma unroll
                for (int t = 0; t < 8; ++t) { p0[t] = f2bf(f[t]); p1[t] = f2bf(f[t+8]); }
                *(bf16x8*)&Ks[r * LDT + cg * 16]     = p0;
                *(bf16x8*)&Ks[r * LDT + cg * 16 + 8] = p1;
            }
            {   // stage G
                const int dd = tid >> 1, hf = tid & 1;
                const int e = 1086 - i0 + j0 - dd;
                short* dst = &Gs[dd * LDT + hf * 32];
                if (e >= 0 && e < 1024) {
                    const float4* src = (const float4*)(eg + (size_t)e * HD + hf * 32);
#pragma unroll
                    for (int u = 0; u < 4; ++u) {
                        float4 a = src[2*u], b = src[2*u + 1];
                        bf16x8 p;
                        p[0] = f2bf(a.x); p[1] = f2bf(a.y); p[2] = f2bf(a.z); p[3] = f2bf(a.w);
                        p[4] = f2bf(b.x); p[5] = f2bf(b.y); p[6] = f2bf(b.z); p[7] = f2bf(b.w);
                        *(bf16x8*)&dst[u * 8] = p;
                    }
                } else {
                    bf16x8 z = {0,0,0,0,0,0,0,0};
#pragma unroll
                    for (int u = 0; u < 4; ++u) *(bf16x8*)&dst[u * 8] = z;
                }
            }
            if (pass == 1) {   // stage V^T
                const int r = tid >> 2, cg = tid & 3;
                const float4* src = (const float4*)(vg + ((size_t)(bh * SEQ + j0 + r)) * HD + cg * 16);
                float f[16];
#pragma unroll
                for (int t = 0; t < 4; ++t) {
                    float4 v4 = src[t];
                    f[4*t] = v4.x; f[4*t+1] = v4.y; f[4*t+2] = v4.z; f[4*t+3] = v4.w;
                }
#pragma unroll
                for (int t = 0; t < 16; ++t) Vt[(cg * 16 + t) * LDT + r] = f2bf(f[t]);
            }
            __syncthreads();

            f32x4 sc[4], tc[5];
#pragma unroll
            for (int ct = 0; ct < 4; ++ct) sc[ct] = zz;
#pragma unroll
            for (int dt = 0; dt < 5; ++dt) tc[dt] = zz;
#pragma unroll
            for (int s = 0; s < 2; ++s) {
                bf16x8 a = aq[s];
#pragma unroll
                for (int ct = 0; ct < 4; ++ct) {
                    bf16x8 b = *(const bf16x8*)&Ks[(ct * 16 + c) * LDT + s * 32 + qd * 8];
                    sc[ct] = __builtin_amdgcn_mfma_f32_16x16x32_bf16(a, b, sc[ct], 0, 0, 0);
                }
#pragma unroll
                for (int dt = 0; dt < 5; ++dt) {
                    bf16x8 g = *(const bf16x8*)&Gs[((wv + dt) * 16 + c) * LDT + s * 32 + qd * 8];
                    tc[dt] = __builtin_amdgcn_mfma_f32_16x16x32_bf16(a, g, tc[dt], 0, 0, 0);
                }
            }
#pragma unroll
            for (int dt = 0; dt < 5; ++dt)
#pragma unroll
                for (int rg = 0; rg < 4; ++rg)
                    Tw[(qd * 4 + rg) * TSTR + dt * 16 + c] = f2bf(tc[dt][rg]);

            if (pass == 0) {
#pragma unroll
                for (int rg = 0; rg < 4; ++rg) {
                    float ss = 0.f;
#pragma unroll
                    for (int ct = 0; ct < 4; ++ct) {
                        const int rl  = qd * 4 + rg;
                        const int ddl = rl + 63 - ct * 16 - c;
                        const float sval = sc[ct][rg] + bf2f(Tw[rl * TSTR + ddl]);
                        const int ig = i0 + wv * 16 + rl;
                        const int jg = j0 + ct * 16 + c;
                        ss += (jg <= ig) ? __expf(sval) : 0.f;
                    }
                    ss += __shfl_xor(ss, 1);
                    ss += __shfl_xor(ss, 2);
                    ss += __shfl_xor(ss, 4);
                    ss += __shfl_xor(ss, 8);
                    lrun[rg] += ss;
                }
            } else {
#pragma unroll
                for (int rg = 0; rg < 4; ++rg) {
                    const int rl = qd * 4 + rg;
                    const int ig = i0 + wv * 16 + rl;
                    float* wrow = Wg + ((size_t)(bh * SEQ + ig)) * SEQ + j0;
#pragma unroll
                    for (int ct = 0; ct < 4; ++ct) {
                        const int ddl = rl + 63 - ct * 16 - c;
                        const float sval = sc[ct][rg] + bf2f(Tw[rl * TSTR + ddl]);
                        const int jg = j0 + ct * 16 + c;
                        const float w = (jg <= ig) ? __expf(sval) * linv[rg] : 0.f;
                        wrow[ct * 16 + c] = w;
                        Tw[rl * TSTR + ct * 16 + c] = f2bf(w);
                    }
                }
#pragma unroll
                for (int s = 0; s < 2; ++s) {
                    bf16x8 ap = *(const bf16x8*)&Tw[c * TSTR + s * 32 + qd * 8];
#pragma unroll
                    for (int dt = 0; dt < 4; ++dt) {
                        bf16x8 bv = *(const bf16x8*)&Vt[(dt * 16 + c) * LDT + s * 32 + qd * 8];
                        ob[dt] = __builtin_amdgcn_mfma_f32_16x16x32_bf16(ap, bv, ob[dt], 0, 0, 0);
                    }
                }
            }
        }
    }

#pragma unroll
    for (int dt = 0; dt < 4; ++dt)
#pragma unroll
        for (int rg = 0; rg < 4; ++rg) {
            const int ig = i0 + wv * 16 + qd * 4 + rg;
            outp[((size_t)(bh * SEQ + ig)) * HD + dt * 16 + c] = ob[dt][rg];
        }
}

extern "C" void kernel_launch(void* const* d_in, const int* in_sizes, int n_in,
                              void* d_out, int out_size, void* d_ws, size_t ws_size,
                              hipStream_t stream) {
    const float* q = (const float*)d_in[0];
    const float* k = (const float*)d_in[1];
    const float* v = (const float*)d_in[2];
    const float* e = (const float*)d_in[3];
    float* out = (float*)d_out;
    if (ws_size >= WS_NEED) {
        short* wsp = (short*)d_ws;
        float* lw  = (float*)((char*)d_ws + WS_L_OFF_B);
        hipLaunchKernelGGL(prep, dim3(1090), dim3(256), 0, stream, k, v, e, wsp);
        hipLaunchKernelGGL(attn, dim3(512),  dim3(256), 0, stream, q, out, wsp, lw);
        hipLaunchKernelGGL(finw, dim3(8192), dim3(256), 0, stream, out, wsp, lw);
    } else {
        hipLaunchKernelGGL(relattn_2p, dim3(512), dim3(256), 0, stream, q, k, v, e, out);
    }
}